// Round 6
// baseline (393.688 us; speedup 1.0000x reference)
//
#include <hip/hip_runtime.h>

#define IMG_H 4096
#define IMG_W 6144

constexpr int SH  = 32;             // rows per wave-strip
constexpr int NSX = IMG_W / 128;    // 48 strips across
constexpr int NSY = IMG_H / SH;     // 128 strips down
// 48*128 = 6144 waves = 1536 blocks of 256 threads

typedef int i2 __attribute__((ext_vector_type(2)));

__device__ __forceinline__ int reflect_h(int r) {
    return r < 0 ? -r : (r >= IMG_H ? 2 * IMG_H - 2 - r : r);
}
__device__ __forceinline__ int clampi(float v) {
    return (int)fminf(fmaxf(v, 0.f), 16777215.f);   // truncate == astype(int32)
}

struct Row { i2 a, b, c; int fix; };

__global__ __launch_bounds__(256)
void demosaic(const int* __restrict__ x, int* __restrict__ out) {
    const int wid  = blockIdx.x * 4 + (threadIdx.x >> 6);
    const int lane = threadIdx.x & 63;
    const int sx = wid >> 7;            // /NSY(128): consecutive waves share a column strip
    const int sy = wid & (NSY - 1);
    const int gx0 = sx * 128;
    const int gy0 = sy * SH;
    const int ce  = gx0 + 2 * lane;     // even col owned by this lane

    const int  cA = max(ce - 2, 0);
    const int  cB = ce;
    const int  cC = min(ce + 2, IMG_W - 2);
    const bool pL = (ce == 0), pR = (ce == IMG_W - 2);
    const bool pat = pL || pR;
    const int  fixc = pL ? 2 : IMG_W - 3;

    auto issue = [&](int y, Row& R) {
        const int* rp = x + (long)reflect_h(y) * IMG_W;
        R.a = *(const i2*)(rp + cA);
        R.b = *(const i2*)(rp + cB);
        R.c = *(const i2*)(rp + cC);
        if (pat) R.fix = rp[fixc];      // 2 lanes in entire grid
    };
    auto consume = [&](const Row& R, float* w6) {
        w6[0] = (float)R.a.x; w6[1] = (float)R.a.y;
        w6[2] = (float)R.b.x; w6[3] = (float)R.b.y;
        w6[4] = (float)R.c.x; w6[5] = (float)R.c.y;
        if (pat) { float f = (float)R.fix; if (pL) w6[0] = f; else w6[5] = f; }
    };

    float w[5][6];
    // ---- prologue: rows gy0-2 .. gy0+1 into w[0..3] ----
    {
        Row t[4];
        #pragma unroll
        for (int i = 0; i < 4; ++i) issue(gy0 - 2 + i, t[i]);
        #pragma unroll
        for (int i = 0; i < 4; ++i) consume(t[i], w[i]);
    }
    Row pr[2];
    issue(gy0 + 2, pr[0]);
    issue(gy0 + 3, pr[1]);

    int* op = out + (long)gy0 * (IMG_W * 3) + ce * 3;

    for (int i = 0; i < SH; i += 2) {
        // ================= even row (even col = R site) =================
        consume(pr[0], w[4]);
        if (i < SH - 2) issue(gy0 + i + 4, pr[0]);
        {
            float Ge = (-w[0][2] + 2.f*(w[1][2]+w[3][2]) + 4.f*w[2][2] - w[4][2]
                        - w[2][0] + 2.f*(w[2][1]+w[2][3]) - w[2][4]) * 0.125f;
            float Ce = (-1.5f*(w[0][2]+w[4][2]+w[2][0]+w[2][4])
                        + 2.f*(w[1][1]+w[1][3]+w[3][1]+w[3][3]) + 6.f*w[2][2]) * 0.125f;
            float RRo = (0.5f*(w[0][3]+w[4][3]) - (w[1][2]+w[1][4]+w[3][2]+w[3][4])
                         - (w[2][1]+w[2][5]) + 4.f*(w[2][2]+w[2][4]) + 5.f*w[2][3]) * 0.125f;
            float RBo = (-(w[0][3]+w[4][3]) - (w[1][2]+w[1][4]+w[3][2]+w[3][4])
                         + 4.f*(w[1][3]+w[3][3]) + 0.5f*(w[2][1]+w[2][5]) + 5.f*w[2][3]) * 0.125f;
            i2 q0, q1, q2;
            q0.x = clampi(w[2][2]); q0.y = clampi(Ge);
            q1.x = clampi(Ce);      q1.y = clampi(RRo);
            q2.x = clampi(w[2][3]); q2.y = clampi(RBo);
            __builtin_nontemporal_store(q0, (i2*)op);
            __builtin_nontemporal_store(q1, (i2*)(op + 2));
            __builtin_nontemporal_store(q2, (i2*)(op + 4));
        }
        #pragma unroll
        for (int r = 0; r < 4; ++r)
            #pragma unroll
            for (int c = 0; c < 6; ++c) w[r][c] = w[r+1][c];
        op += IMG_W * 3;

        // ================= odd row (odd col = B site) =================
        consume(pr[1], w[4]);
        if (i < SH - 3) issue(gy0 + i + 5, pr[1]);
        {
            float RBe = (-(w[0][2]+w[4][2]) - (w[1][1]+w[1][3]+w[3][1]+w[3][3])
                         + 4.f*(w[1][2]+w[3][2]) + 0.5f*(w[2][0]+w[2][4]) + 5.f*w[2][2]) * 0.125f;
            float RRe = (0.5f*(w[0][2]+w[4][2]) - (w[1][1]+w[1][3]+w[3][1]+w[3][3])
                         - (w[2][0]+w[2][4]) + 4.f*(w[2][1]+w[2][3]) + 5.f*w[2][2]) * 0.125f;
            float Co  = (-1.5f*(w[0][3]+w[4][3]+w[2][1]+w[2][5])
                         + 2.f*(w[1][2]+w[1][4]+w[3][2]+w[3][4]) + 6.f*w[2][3]) * 0.125f;
            float Go  = (-w[0][3] + 2.f*(w[1][3]+w[3][3]) + 4.f*w[2][3] - w[4][3]
                         - w[2][1] + 2.f*(w[2][2]+w[2][4]) - w[2][5]) * 0.125f;
            i2 q0, q1, q2;
            q0.x = clampi(RBe);     q0.y = clampi(w[2][2]);
            q1.x = clampi(RRe);     q1.y = clampi(Co);
            q2.x = clampi(Go);      q2.y = clampi(w[2][3]);
            __builtin_nontemporal_store(q0, (i2*)op);
            __builtin_nontemporal_store(q1, (i2*)(op + 2));
            __builtin_nontemporal_store(q2, (i2*)(op + 4));
        }
        #pragma unroll
        for (int r = 0; r < 4; ++r)
            #pragma unroll
            for (int c = 0; c < 6; ++c) w[r][c] = w[r+1][c];
        op += IMG_W * 3;
    }
}

extern "C" void kernel_launch(void* const* d_in, const int* in_sizes, int n_in,
                              void* d_out, int out_size, void* d_ws, size_t ws_size,
                              hipStream_t stream) {
    const int* x = (const int*)d_in[0];
    int* out = (int*)d_out;
    demosaic<<<NSX * NSY / 4, 256, 0, stream>>>(x, out);   // 1536 blocks
}

// Round 9
// 380.156 us; speedup vs baseline: 1.0356x; 1.0356x over previous
//
#include <hip/hip_runtime.h>

#define IMG_H 4096
#define IMG_W 6144

constexpr int SH  = 32;             // rows per wave-strip
constexpr int NSX = IMG_W / 128;    // 48 strips across
constexpr int NSY = IMG_H / SH;     // 128 strips down
constexpr int RS  = IMG_W * 3;      // output row stride in ints

typedef int i2 __attribute__((ext_vector_type(2)));
typedef int i4 __attribute__((ext_vector_type(4)));

__device__ __forceinline__ int reflect_h(int r) {
    return r < 0 ? -r : (r >= IMG_H ? 2 * IMG_H - 2 - r : r);
}
__device__ __forceinline__ int clampi(float v) {
    return (int)fminf(fmaxf(v, 0.f), 16777215.f);   // truncate == astype(int32)
}

struct Row { i2 a, b, c; int fix; };

__global__ __launch_bounds__(256)
void demosaic(const int* __restrict__ x, int* __restrict__ out) {
    // per-wave DOUBLE-buffered repack area: 4 waves x 2 bufs x 768 ints = 24 KB
    __shared__ __align__(16) int sbuf[4][2][768];

    const int tid  = threadIdx.x;
    const int wv   = tid >> 6;
    const int wid  = blockIdx.x * 4 + wv;
    const int lane = tid & 63;

    const int sx = wid >> 7;            // consecutive waves share a column strip
    const int sy = wid & (NSY - 1);
    const int gx0 = sx * 128;
    const int gy0 = sy * SH;
    const int ce  = gx0 + 2 * lane;     // even col owned by this lane

    const int  cA = max(ce - 2, 0);
    const int  cB = ce;
    const int  cC = min(ce + 2, IMG_W - 2);
    const bool pL = (ce == 0), pR = (ce == IMG_W - 2);
    const bool pat = pL || pR;
    const int  fixc = pL ? 2 : IMG_W - 3;

    auto issue = [&](int y, Row& R) {
        const int* rp = x + (long)reflect_h(y) * IMG_W;
        R.a = *(const i2*)(rp + cA);
        R.b = *(const i2*)(rp + cB);
        R.c = *(const i2*)(rp + cC);
        if (pat) R.fix = rp[fixc];      // 2 lanes in entire grid
    };
    auto consume = [&](const Row& R, float* w6) {
        w6[0] = (float)R.a.x; w6[1] = (float)R.a.y;
        w6[2] = (float)R.b.x; w6[3] = (float)R.b.y;
        w6[4] = (float)R.c.x; w6[5] = (float)R.c.y;
        if (pat) { float f = (float)R.fix; if (pL) w6[0] = f; else w6[5] = f; }
    };

    // copyout descriptors: logical int j = c*256 + 4*lane in [0,768)
    // j<384 -> out row i, col j ; else -> out row i+1, col j-384
    int doff[3];
    #pragma unroll
    for (int c = 0; c < 3; ++c) {
        int off = c * 256 + 4 * lane;
        doff[c] = (off >= 384) ? (off - 384 + RS) : off;
    }

    float w[6][6];
    // ---- prologue: rows gy0-2..gy0+1 -> w[0..3]; ring <- rows gy0+2..gy0+5 ----
    {
        Row t0, t1, t2, t3;
        issue(gy0 - 2, t0); issue(gy0 - 1, t1);
        issue(gy0 + 0, t2); issue(gy0 + 1, t3);
        consume(t0, w[0]); consume(t1, w[1]);
        consume(t2, w[2]); consume(t3, w[3]);
    }
    Row pr0, pr1, pr2, pr3;
    issue(gy0 + 2, pr0); issue(gy0 + 3, pr1);
    issue(gy0 + 4, pr2); issue(gy0 + 5, pr3);

    int* op = out + (long)gy0 * RS + gx0 * 3;   // block-col base of row pair

    auto body = [&](int i, Row& A, Row& B, int* sb) {
        consume(A, w[4]);                        // input row gy0+i+2
        consume(B, w[5]);                        // input row gy0+i+3
        if (i + 6 <= SH + 1) issue(gy0 + i + 6, A);
        if (i + 7 <= SH + 1) issue(gy0 + i + 7, B);

        // ---- even output row i: window w[0..4], center w[2] ----
        {
            float Ge = (-w[0][2] + 2.f*(w[1][2]+w[3][2]) + 4.f*w[2][2] - w[4][2]
                        - w[2][0] + 2.f*(w[2][1]+w[2][3]) - w[2][4]) * 0.125f;
            float Ce = (-1.5f*(w[0][2]+w[4][2]+w[2][0]+w[2][4])
                        + 2.f*(w[1][1]+w[1][3]+w[3][1]+w[3][3]) + 6.f*w[2][2]) * 0.125f;
            float RRo = (0.5f*(w[0][3]+w[4][3]) - (w[1][2]+w[1][4]+w[3][2]+w[3][4])
                         - (w[2][1]+w[2][5]) + 4.f*(w[2][2]+w[2][4]) + 5.f*w[2][3]) * 0.125f;
            float RBo = (-(w[0][3]+w[4][3]) - (w[1][2]+w[1][4]+w[3][2]+w[3][4])
                         + 4.f*(w[1][3]+w[3][3]) + 0.5f*(w[2][1]+w[2][5]) + 5.f*w[2][3]) * 0.125f;
            i2 q;
            q.x = clampi(w[2][2]); q.y = clampi(Ge);  *(i2*)&sb[6*lane + 0] = q;
            q.x = clampi(Ce);      q.y = clampi(RRo); *(i2*)&sb[6*lane + 2] = q;
            q.x = clampi(w[2][3]); q.y = clampi(RBo); *(i2*)&sb[6*lane + 4] = q;
        }
        // ---- odd output row i+1: window w[1..5], center w[3] ----
        {
            float RBe = (-(w[1][2]+w[5][2]) - (w[2][1]+w[2][3]+w[4][1]+w[4][3])
                         + 4.f*(w[2][2]+w[4][2]) + 0.5f*(w[3][0]+w[3][4]) + 5.f*w[3][2]) * 0.125f;
            float RRe = (0.5f*(w[1][2]+w[5][2]) - (w[2][1]+w[2][3]+w[4][1]+w[4][3])
                         - (w[3][0]+w[3][4]) + 4.f*(w[3][1]+w[3][3]) + 5.f*w[3][2]) * 0.125f;
            float Co  = (-1.5f*(w[1][3]+w[5][3]+w[3][1]+w[3][5])
                         + 2.f*(w[2][2]+w[2][4]+w[4][2]+w[4][4]) + 6.f*w[3][3]) * 0.125f;
            float Go  = (-w[1][3] + 2.f*(w[2][3]+w[4][3]) + 4.f*w[3][3] - w[5][3]
                         - w[3][1] + 2.f*(w[3][2]+w[3][4]) - w[3][5]) * 0.125f;
            i2 q;
            q.x = clampi(RBe);     q.y = clampi(w[3][2]); *(i2*)&sb[384 + 6*lane + 0] = q;
            q.x = clampi(RRe);     q.y = clampi(Co);      *(i2*)&sb[384 + 6*lane + 2] = q;
            q.x = clampi(Go);      q.y = clampi(w[3][3]); *(i2*)&sb[384 + 6*lane + 4] = q;
        }

        // ---- ORDER: all ds_writes complete before any cross-lane ds_read ----
        asm volatile("s_waitcnt lgkmcnt(0)" ::: "memory");
        __builtin_amdgcn_sched_barrier(0);

        // ---- wave-private copyout: 3 x 1024B fully-coalesced NT stores ----
        #pragma unroll
        for (int c = 0; c < 3; ++c) {
            i2 lo = *(const i2*)&sb[c * 256 + 4 * lane];
            i2 hi = *(const i2*)&sb[c * 256 + 4 * lane + 2];
            i4 q; q.x = lo.x; q.y = lo.y; q.z = hi.x; q.w = hi.y;
            __builtin_nontemporal_store(q, (i4*)(op + doff[c]));
        }
        asm volatile("" ::: "memory");   // keep reads before next body's writes
        op += 2 * RS;

        // ---- shift window down 2 rows ----
        #pragma unroll
        for (int r = 0; r < 4; ++r)
            #pragma unroll
            for (int c6 = 0; c6 < 6; ++c6) w[r][c6] = w[r + 2][c6];
    };

    int* sb0 = sbuf[wv][0];
    int* sb1 = sbuf[wv][1];
    for (int i = 0; i < SH; i += 4) {
        body(i,     pr0, pr1, sb0);   // ping
        body(i + 2, pr2, pr3, sb1);   // pong
    }
}

extern "C" void kernel_launch(void* const* d_in, const int* in_sizes, int n_in,
                              void* d_out, int out_size, void* d_ws, size_t ws_size,
                              hipStream_t stream) {
    const int* x = (const int*)d_in[0];
    int* out = (int*)d_out;
    demosaic<<<NSX * NSY / 4, 256, 0, stream>>>(x, out);   // 1536 blocks
}